// Round 1
// baseline (4070.889 us; speedup 1.0000x reference)
//
#include <hip/hip_runtime.h>
#include <math.h>

#define LOG2F 0.6931471805599453f

__device__ __forceinline__ float sspf(float x) {
    // shifted softplus: log(1+exp(x)) - log(2), numerically stable
    return fmaxf(x, 0.0f) + log1pf(expf(-fabsf(x))) - LOG2F;
}

// Y[r][c] = act( sum_k X[r][k] * W[k][c] + b[c] )
// ACT 0: none; 1: tanh(ssp(.))
template<int ACT>
__global__ void node_gemm(const float* __restrict__ X, const float* __restrict__ W,
                          const float* __restrict__ b, float* __restrict__ Y, int N) {
    __shared__ float xs[2][128];
    const int tid = threadIdx.x;
    const int r = tid >> 7;       // 0..1
    const int c = tid & 127;      // 0..127
    const int row = blockIdx.x * 2 + r;
    if (row < N) xs[r][c] = X[(size_t)row * 128 + c];
    __syncthreads();
    if (row >= N) return;
    float acc = b[c];
#pragma unroll 8
    for (int k = 0; k < 128; ++k)
        acc = fmaf(xs[r][k], W[k * 128 + c], acc);
    if (ACT) acc = tanhf(sspf(acc));
    Y[(size_t)row * 128 + c] = acc;
}

// One wave (64 lanes) per edge. Each lane owns channels {lane, lane+64}.
// t1 = ssp(e @ W1 + b1); he = ssp(t1 @ W2 + b2); msg = hv[src]*he; atomicAdd agg[dst].
__global__ void edge_kernel(const float* __restrict__ E, const int* __restrict__ src,
                            const int* __restrict__ dst, const float* __restrict__ HV,
                            const float* __restrict__ W1, const float* __restrict__ b1,
                            const float* __restrict__ W2, const float* __restrict__ b2,
                            float* __restrict__ AGG, int nEdges) {
    __shared__ float sh[4][192];      // per wave: e-row[64] + t1[128]
    const int wid  = threadIdx.x >> 6;
    const int lane = threadIdx.x & 63;
    float* erow = &sh[wid][0];
    float* t1   = &sh[wid][64];
    const int gwave  = blockIdx.x * 4 + wid;
    const int nwaves = gridDim.x * 4;

    for (int e = gwave; e < nEdges; e += nwaves) {
        // stage edge feature row (64 f32) in LDS (wave-synchronous, no barrier needed)
        erow[lane] = E[(size_t)e * 64 + lane];

        float a0 = b1[lane], a1 = b1[lane + 64];
#pragma unroll 8
        for (int k = 0; k < 64; ++k) {
            const float ev = erow[k];                 // LDS broadcast
            a0 = fmaf(ev, W1[k * 128 + lane],      a0);
            a1 = fmaf(ev, W1[k * 128 + lane + 64], a1);
        }
        t1[lane]      = sspf(a0);
        t1[lane + 64] = sspf(a1);

        float h0 = b2[lane], h1 = b2[lane + 64];
#pragma unroll 8
        for (int k = 0; k < 128; ++k) {
            const float tv = t1[k];                   // LDS broadcast
            h0 = fmaf(tv, W2[k * 128 + lane],      h0);
            h1 = fmaf(tv, W2[k * 128 + lane + 64], h1);
        }
        h0 = sspf(h0);
        h1 = sspf(h1);

        const int s = src[e], d = dst[e];
        const float m0 = HV[(size_t)s * 128 + lane]      * h0;
        const float m1 = HV[(size_t)s * 128 + lane + 64] * h1;
        atomicAdd(&AGG[(size_t)d * 128 + lane],      m0);
        atomicAdd(&AGG[(size_t)d * 128 + lane + 64], m1);
    }
}

extern "C" void kernel_launch(void* const* d_in, const int* in_sizes, int n_in,
                              void* d_out, int out_size, void* d_ws, size_t ws_size,
                              hipStream_t stream) {
    const float* x    = (const float*)d_in[0];
    const float* e    = (const float*)d_in[1];
    const int*   src  = (const int*)  d_in[2];
    const int*   dst  = (const int*)  d_in[3];
    const float* n1W  = (const float*)d_in[4];
    const float* n1b  = (const float*)d_in[5];
    const float* e1W1 = (const float*)d_in[6];
    const float* e1b1 = (const float*)d_in[7];
    const float* e1W2 = (const float*)d_in[8];
    const float* e1b2 = (const float*)d_in[9];
    const float* o1W  = (const float*)d_in[10];
    const float* o1b  = (const float*)d_in[11];
    const float* n2W  = (const float*)d_in[12];
    const float* n2b  = (const float*)d_in[13];
    const float* e2W1 = (const float*)d_in[14];
    const float* e2b1 = (const float*)d_in[15];
    const float* e2W2 = (const float*)d_in[16];
    const float* e2b2 = (const float*)d_in[17];
    const float* o2W  = (const float*)d_in[18];
    const float* o2b  = (const float*)d_in[19];

    const int N = in_sizes[0] / 128;
    const int E = in_sizes[2];
    float* out = (float*)d_out;

    char* ws = (char*)d_ws;
    const size_t nbytes = (size_t)N * 128 * sizeof(float);
    float* hv   = (float*)(ws);                 // [N,128]
    float* agg  = (float*)(ws + nbytes);        // [N,128]
    float* hbuf = (float*)(ws + 2 * nbytes);    // [N,128]

    const int nodeBlocks = (N + 1) / 2;
    const int edgeBlocks = 2048;

    // ---- layer 1 ----
    node_gemm<0><<<nodeBlocks, 256, 0, stream>>>(x, n1W, n1b, hv, N);
    hipMemsetAsync(agg, 0, nbytes, stream);
    edge_kernel<<<edgeBlocks, 256, 0, stream>>>(e, src, dst, hv, e1W1, e1b1, e1W2, e1b2, agg, E);
    node_gemm<1><<<nodeBlocks, 256, 0, stream>>>(agg, o1W, o1b, hbuf, N);

    // ---- layer 2 ----
    node_gemm<0><<<nodeBlocks, 256, 0, stream>>>(hbuf, n2W, n2b, hv, N);
    hipMemsetAsync(agg, 0, nbytes, stream);
    edge_kernel<<<edgeBlocks, 256, 0, stream>>>(e, src, dst, hv, e2W1, e2b1, e2W2, e2b2, agg, E);
    node_gemm<1><<<nodeBlocks, 256, 0, stream>>>(agg, o2W, o2b, out, N);
}

// Round 4
// 1000.129 us; speedup vs baseline: 4.0704x; 4.0704x over previous
//
#include <hip/hip_runtime.h>
#include <hip/hip_bf16.h>
#include <math.h>

typedef __bf16 bf16x8 __attribute__((ext_vector_type(8)));
typedef float f32x4 __attribute__((ext_vector_type(4)));

#define LOG2F 0.6931471805599453f
#define PK1 72     // padded row length (bf16) for K=64 tiles  (144 B, 16B-aligned rows)
#define PK2 136    // padded row length (bf16) for K=128 tiles (272 B, 16B-aligned rows)

__device__ __forceinline__ float sspf(float x) {
    // shifted softplus: log(1+exp(x)) - log(2), numerically stable
    return fmaxf(x, 0.0f) + log1pf(expf(-fabsf(x))) - LOG2F;
}

// float -> bf16 (round-to-nearest-even) bit pattern
__device__ __forceinline__ unsigned short f2bf(float f) {
    union { float f; unsigned u; } v; v.f = f;
    unsigned r = v.u + 0x7FFF + ((v.u >> 16) & 1);
    return (unsigned short)(r >> 16);
}

// ---------------- node GEMM (f32, unchanged from R1) ----------------
template<int ACT>
__global__ void node_gemm(const float* __restrict__ X, const float* __restrict__ W,
                          const float* __restrict__ b, float* __restrict__ Y, int N) {
    __shared__ float xs[2][128];
    const int tid = threadIdx.x;
    const int r = tid >> 7;
    const int c = tid & 127;
    const int row = blockIdx.x * 2 + r;
    if (row < N) xs[r][c] = X[(size_t)row * 128 + c];
    __syncthreads();
    if (row >= N) return;
    float acc = b[c];
#pragma unroll 8
    for (int k = 0; k < 128; ++k)
        acc = fmaf(xs[r][k], W[k * 128 + c], acc);
    if (ACT) acc = tanhf(sspf(acc));
    Y[(size_t)row * 128 + c] = acc;
}

// ---------------- weight pre-convert: W[k][128] f32 -> W^T[n][PK] bf16 (padded) ----------------
__global__ void convert_wT(const float* __restrict__ W, unsigned short* __restrict__ O,
                           int K, int PK) {
    int idx = blockIdx.x * 256 + threadIdx.x;
    if (idx >= 128 * PK) return;
    int n = idx / PK, k = idx - n * PK;
    O[idx] = (k < K) ? f2bf(W[k * 128 + n]) : (unsigned short)0;
}

// ---------------- fused edge MLP (MFMA) + gather/filter/scatter ----------------
// Block = 256 threads (4 waves), tile = 64 edges. Wave w owns output cols [w*32, w*32+32).
__global__ __launch_bounds__(256) void edge_mfma(
    const float* __restrict__ E, const int* __restrict__ src, const int* __restrict__ dst,
    const float* __restrict__ HV,
    const unsigned short* __restrict__ W1T, const float* __restrict__ b1,
    const unsigned short* __restrict__ W2T, const float* __restrict__ b2,
    float* __restrict__ AGG, int nE)
{
    __shared__ unsigned short sE[64 * PK1];    // 9216 B   edge-feature tile (bf16)
    __shared__ unsigned short sT1[64 * PK2];   // 17408 B  hidden tile (bf16)
    __shared__ int sSrc[64], sDst[64];

    const int tid = threadIdx.x;
    const int e0 = blockIdx.x * 64;

    // ---- stage E tile (f32 -> bf16), src/dst indices ----
    {
        const int r = tid >> 2;                 // 0..63
        const int c0 = (tid & 3) * 16;          // 0,16,32,48
        unsigned short* drow = &sE[r * PK1 + c0];
        if (e0 + r < nE) {
            const float4* s4 = (const float4*)&E[(size_t)(e0 + r) * 64 + c0];
#pragma unroll
            for (int j = 0; j < 4; ++j) {
                float4 v = s4[j];
                drow[j * 4 + 0] = f2bf(v.x); drow[j * 4 + 1] = f2bf(v.y);
                drow[j * 4 + 2] = f2bf(v.z); drow[j * 4 + 3] = f2bf(v.w);
            }
        } else {
#pragma unroll
            for (int j = 0; j < 16; ++j) drow[j] = 0;
        }
        if (tid < 64) {
            int e = e0 + tid;
            sSrc[tid] = (e < nE) ? src[e] : 0;
            sDst[tid] = (e < nE) ? dst[e] : 0;
        }
    }
    __syncthreads();

    const int w  = tid >> 6;          // wave id 0..3
    const int l  = tid & 63;          // lane
    const int cb = w * 32;            // column base for this wave
    const int lr = l & 15;            // fragment row/col index
    const int lk = (l >> 4) * 8;      // fragment k base

    // ---- B1 fragments from global W1T (L2-resident, one-time) ----
    bf16x8 B1[2][2];
#pragma unroll
    for (int nt = 0; nt < 2; ++nt)
#pragma unroll
        for (int kt = 0; kt < 2; ++kt)
            B1[nt][kt] = *(const bf16x8*)&W1T[(cb + nt * 16 + lr) * PK1 + kt * 32 + lk];

    // ---- GEMM1: T1 = ssp(E @ W1 + b1) ----
    f32x4 acc1[4][2] = {};
#pragma unroll
    for (int kt = 0; kt < 2; ++kt)
#pragma unroll
        for (int mt = 0; mt < 4; ++mt) {
            bf16x8 A = *(const bf16x8*)&sE[(mt * 16 + lr) * PK1 + kt * 32 + lk];
#pragma unroll
            for (int nt = 0; nt < 2; ++nt)
                acc1[mt][nt] = __builtin_amdgcn_mfma_f32_16x16x32_bf16(A, B1[nt][kt], acc1[mt][nt], 0, 0, 0);
        }

    const float bb1[2] = { b1[cb + lr], b1[cb + 16 + lr] };
#pragma unroll
    for (int mt = 0; mt < 4; ++mt)
#pragma unroll
        for (int nt = 0; nt < 2; ++nt) {
            const int col = cb + nt * 16 + lr;
#pragma unroll
            for (int r = 0; r < 4; ++r) {
                const int row = mt * 16 + (l >> 4) * 4 + r;
                sT1[row * PK2 + col] = f2bf(sspf(acc1[mt][nt][r] + bb1[nt]));
            }
        }
    __syncthreads();

    // ---- B2 fragments from global W2T ----
    bf16x8 B2[2][4];
#pragma unroll
    for (int nt = 0; nt < 2; ++nt)
#pragma unroll
        for (int kt = 0; kt < 4; ++kt)
            B2[nt][kt] = *(const bf16x8*)&W2T[(cb + nt * 16 + lr) * PK2 + kt * 32 + lk];

    // ---- GEMM2: he = ssp(T1 @ W2 + b2) ----
    f32x4 acc2[4][2] = {};
#pragma unroll
    for (int kt = 0; kt < 4; ++kt)
#pragma unroll
        for (int mt = 0; mt < 4; ++mt) {
            bf16x8 A = *(const bf16x8*)&sT1[(mt * 16 + lr) * PK2 + kt * 32 + lk];
#pragma unroll
            for (int nt = 0; nt < 2; ++nt)
                acc2[mt][nt] = __builtin_amdgcn_mfma_f32_16x16x32_bf16(A, B2[nt][kt], acc2[mt][nt], 0, 0, 0);
        }

    // ---- epilogue: msg = hv[src] * he ; atomicAdd agg[dst] ----
    const float bb2[2] = { b2[cb + lr], b2[cb + 16 + lr] };
#pragma unroll
    for (int mt = 0; mt < 4; ++mt)
#pragma unroll
        for (int nt = 0; nt < 2; ++nt) {
            const int col = cb + nt * 16 + lr;
#pragma unroll
            for (int r = 0; r < 4; ++r) {
                const int row = mt * 16 + (l >> 4) * 4 + r;
                if (e0 + row < nE) {
                    const float he = sspf(acc2[mt][nt][r] + bb2[nt]);
                    const int s = sSrc[row], d = sDst[row];
                    const float m = HV[(size_t)s * 128 + col] * he;
                    atomicAdd(&AGG[(size_t)d * 128 + col], m);
                }
            }
        }
}

extern "C" void kernel_launch(void* const* d_in, const int* in_sizes, int n_in,
                              void* d_out, int out_size, void* d_ws, size_t ws_size,
                              hipStream_t stream) {
    const float* x    = (const float*)d_in[0];
    const float* e    = (const float*)d_in[1];
    const int*   src  = (const int*)  d_in[2];
    const int*   dst  = (const int*)  d_in[3];
    const float* n1W  = (const float*)d_in[4];
    const float* n1b  = (const float*)d_in[5];
    const float* e1W1 = (const float*)d_in[6];
    const float* e1b1 = (const float*)d_in[7];
    const float* e1W2 = (const float*)d_in[8];
    const float* e1b2 = (const float*)d_in[9];
    const float* o1W  = (const float*)d_in[10];
    const float* o1b  = (const float*)d_in[11];
    const float* n2W  = (const float*)d_in[12];
    const float* n2b  = (const float*)d_in[13];
    const float* e2W1 = (const float*)d_in[14];
    const float* e2b1 = (const float*)d_in[15];
    const float* e2W2 = (const float*)d_in[16];
    const float* e2b2 = (const float*)d_in[17];
    const float* o2W  = (const float*)d_in[18];
    const float* o2b  = (const float*)d_in[19];

    const int N = in_sizes[0] / 128;
    const int E = in_sizes[2];
    float* out = (float*)d_out;

    char* ws = (char*)d_ws;
    const size_t nbytes = (size_t)N * 128 * sizeof(float);
    float* hv   = (float*)(ws);
    float* agg  = (float*)(ws + nbytes);
    float* hbuf = (float*)(ws + 2 * nbytes);

    // converted-weight buffers (bf16, transposed+padded): 2*(9216+17408)*2B = 106.5 KB
    const size_t w1t_elems = 128 * PK1;   // 9216
    const size_t w2t_elems = 128 * PK2;   // 17408
    const size_t wbytes = 2 * (w1t_elems + w2t_elems) * sizeof(unsigned short);
    unsigned short* wbase;
    if (ws_size >= 3 * nbytes + wbytes) {
        wbase = (unsigned short*)(ws + 3 * nbytes);
    } else {
        // fall back to using d_out as scratch: edge kernels finish before the
        // final node_gemm overwrites all of d_out.
        wbase = (unsigned short*)d_out;
    }
    unsigned short* w1t_1 = wbase;
    unsigned short* w2t_1 = wbase + w1t_elems;
    unsigned short* w1t_2 = wbase + w1t_elems + w2t_elems;
    unsigned short* w2t_2 = wbase + 2 * w1t_elems + w2t_elems;

    const int nodeBlocks = (N + 1) / 2;
    const int edgeBlocks = (E + 63) / 64;

    // pre-convert weights
    convert_wT<<<(128 * PK1 + 255) / 256, 256, 0, stream>>>(e1W1, w1t_1, 64,  PK1);
    convert_wT<<<(128 * PK2 + 255) / 256, 256, 0, stream>>>(e1W2, w2t_1, 128, PK2);
    convert_wT<<<(128 * PK1 + 255) / 256, 256, 0, stream>>>(e2W1, w1t_2, 64,  PK1);
    convert_wT<<<(128 * PK2 + 255) / 256, 256, 0, stream>>>(e2W2, w2t_2, 128, PK2);

    // ---- layer 1 ----
    node_gemm<0><<<nodeBlocks, 256, 0, stream>>>(x, n1W, n1b, hv, N);
    hipMemsetAsync(agg, 0, nbytes, stream);
    edge_mfma<<<edgeBlocks, 256, 0, stream>>>(e, src, dst, hv, w1t_1, e1b1, w2t_1, e1b2, agg, E);
    node_gemm<1><<<nodeBlocks, 256, 0, stream>>>(agg, o1W, o1b, hbuf, N);

    // ---- layer 2 ----
    node_gemm<0><<<nodeBlocks, 256, 0, stream>>>(hbuf, n2W, n2b, hv, N);
    hipMemsetAsync(agg, 0, nbytes, stream);
    edge_mfma<<<edgeBlocks, 256, 0, stream>>>(e, src, dst, hv, w1t_2, e2b1, w2t_2, e2b2, agg, E);
    node_gemm<1><<<nodeBlocks, 256, 0, stream>>>(agg, o2W, o2b, out, N);
}

// Round 5
// 753.234 us; speedup vs baseline: 5.4045x; 1.3278x over previous
//
#include <hip/hip_runtime.h>
#include <hip/hip_bf16.h>
#include <math.h>

typedef __bf16 bf16x8 __attribute__((ext_vector_type(8)));
typedef float f32x4 __attribute__((ext_vector_type(4)));

#define LOG2F 0.6931471805599453f
#define PK1 72     // padded row length (bf16) for K=64 tiles  (144 B, 16B-aligned rows)
#define PK2 136    // padded row length (bf16) for K=128 tiles (272 B, 16B-aligned rows)

// fast shifted softplus: log(1+exp(x)) - log(2), numerically stable.
// __expf/__logf -> v_exp_f32/v_log_f32 (hw transcendentals), ~2ulp — far below
// the bf16 noise floor already present.
__device__ __forceinline__ float sspf(float x) {
    float t = __expf(-fabsf(x));
    return fmaxf(x, 0.0f) + __logf(1.0f + t) - LOG2F;
}

// slow-but-exact f32->bf16 RNE (used only in one-time weight convert)
__device__ __forceinline__ unsigned short f2bf(float f) {
    union { float f; unsigned u; } v; v.f = f;
    unsigned r = v.u + 0x7FFF + ((v.u >> 16) & 1);
    return (unsigned short)(r >> 16);
}

// fast hw convert for hot paths
__device__ __forceinline__ unsigned short f2bf_fast(float f) {
    __bf16 h = (__bf16)f;
    return __builtin_bit_cast(unsigned short, h);
}

// ---------------- node GEMM (f32) ----------------
template<int ACT>
__global__ void node_gemm(const float* __restrict__ X, const float* __restrict__ W,
                          const float* __restrict__ b, float* __restrict__ Y, int N) {
    __shared__ float xs[2][128];
    const int tid = threadIdx.x;
    const int r = tid >> 7;
    const int c = tid & 127;
    const int row = blockIdx.x * 2 + r;
    if (row < N) xs[r][c] = X[(size_t)row * 128 + c];
    __syncthreads();
    if (row >= N) return;
    float acc = b[c];
#pragma unroll 8
    for (int k = 0; k < 128; ++k)
        acc = fmaf(xs[r][k], W[k * 128 + c], acc);
    if (ACT) acc = tanhf(sspf(acc));
    Y[(size_t)row * 128 + c] = acc;
}

// ---------------- weight pre-convert: W[k][128] f32 -> W^T[n][PK] bf16 (padded) ----------------
__global__ void convert_wT(const float* __restrict__ W, unsigned short* __restrict__ O,
                           int K, int PK) {
    int idx = blockIdx.x * 256 + threadIdx.x;
    if (idx >= 128 * PK) return;
    int n = idx / PK, k = idx - n * PK;
    O[idx] = (k < K) ? f2bf(W[k * 128 + n]) : (unsigned short)0;
}

// ---------------- fused edge MLP (MFMA) + gather/filter/scatter ----------------
// Block = 256 threads (4 waves), tile = 64 edges. Wave w owns output cols [w*32, w*32+32).
__global__ __launch_bounds__(256) void edge_mfma(
    const float* __restrict__ E, const int* __restrict__ src, const int* __restrict__ dst,
    const float* __restrict__ HV,
    const unsigned short* __restrict__ W1T, const float* __restrict__ b1,
    const unsigned short* __restrict__ W2T, const float* __restrict__ b2,
    float* __restrict__ AGG, int nE)
{
    __shared__ unsigned short sE[64 * PK1];    // 9216 B   edge-feature tile (bf16)
    __shared__ unsigned short sT1[64 * PK2];   // 17408 B  hidden tile (bf16)
    __shared__ int sSrc[64], sDst[64];

    const int tid = threadIdx.x;
    const int e0 = blockIdx.x * 64;

    // ---- stage E tile (f32 -> bf16), src/dst indices ----
    {
        const int r = tid >> 2;                 // 0..63
        const int c0 = (tid & 3) * 16;          // 0,16,32,48
        unsigned short* drow = &sE[r * PK1 + c0];
        if (e0 + r < nE) {
            const float4* s4 = (const float4*)&E[(size_t)(e0 + r) * 64 + c0];
#pragma unroll
            for (int j = 0; j < 4; ++j) {
                float4 v = s4[j];
                drow[j * 4 + 0] = f2bf_fast(v.x); drow[j * 4 + 1] = f2bf_fast(v.y);
                drow[j * 4 + 2] = f2bf_fast(v.z); drow[j * 4 + 3] = f2bf_fast(v.w);
            }
        } else {
#pragma unroll
            for (int j = 0; j < 16; ++j) drow[j] = 0;
        }
        if (tid < 64) {
            int e = e0 + tid;
            sSrc[tid] = (e < nE) ? src[e] : 0;
            sDst[tid] = (e < nE) ? dst[e] : 0;
        }
    }
    __syncthreads();

    const int w  = tid >> 6;          // wave id 0..3
    const int l  = tid & 63;          // lane
    const int cb = w * 32;            // column base for this wave
    const int lr = l & 15;            // fragment row/col index
    const int lk = (l >> 4) * 8;      // fragment k base

    // ---- B1 fragments from global W1T (L2-resident, one-time) ----
    bf16x8 B1[2][2];
#pragma unroll
    for (int nt = 0; nt < 2; ++nt)
#pragma unroll
        for (int kt = 0; kt < 2; ++kt)
            B1[nt][kt] = *(const bf16x8*)&W1T[(cb + nt * 16 + lr) * PK1 + kt * 32 + lk];

    const float bb1[2] = { b1[cb + lr], b1[cb + 16 + lr] };
    const float bb2[2] = { b2[cb + lr], b2[cb + 16 + lr] };

    // ---- GEMM1: T1 = ssp(E @ W1 + b1) ----  (bias pre-loaded into accumulator)
    f32x4 acc1[4][2];
#pragma unroll
    for (int mt = 0; mt < 4; ++mt)
#pragma unroll
        for (int nt = 0; nt < 2; ++nt)
            acc1[mt][nt] = (f32x4){bb1[nt], bb1[nt], bb1[nt], bb1[nt]};
#pragma unroll
    for (int kt = 0; kt < 2; ++kt)
#pragma unroll
        for (int mt = 0; mt < 4; ++mt) {
            bf16x8 A = *(const bf16x8*)&sE[(mt * 16 + lr) * PK1 + kt * 32 + lk];
#pragma unroll
            for (int nt = 0; nt < 2; ++nt)
                acc1[mt][nt] = __builtin_amdgcn_mfma_f32_16x16x32_bf16(A, B1[nt][kt], acc1[mt][nt], 0, 0, 0);
        }

#pragma unroll
    for (int mt = 0; mt < 4; ++mt)
#pragma unroll
        for (int nt = 0; nt < 2; ++nt) {
            const int col = cb + nt * 16 + lr;
#pragma unroll
            for (int r = 0; r < 4; ++r) {
                const int row = mt * 16 + (l >> 4) * 4 + r;
                sT1[row * PK2 + col] = f2bf_fast(sspf(acc1[mt][nt][r]));
            }
        }
    __syncthreads();

    // ---- B2 fragments from global W2T ----
    bf16x8 B2[2][4];
#pragma unroll
    for (int nt = 0; nt < 2; ++nt)
#pragma unroll
        for (int kt = 0; kt < 4; ++kt)
            B2[nt][kt] = *(const bf16x8*)&W2T[(cb + nt * 16 + lr) * PK2 + kt * 32 + lk];

    // ---- GEMM2: he = ssp(T1 @ W2 + b2) ----
    f32x4 acc2[4][2];
#pragma unroll
    for (int mt = 0; mt < 4; ++mt)
#pragma unroll
        for (int nt = 0; nt < 2; ++nt)
            acc2[mt][nt] = (f32x4){bb2[nt], bb2[nt], bb2[nt], bb2[nt]};
#pragma unroll
    for (int kt = 0; kt < 4; ++kt)
#pragma unroll
        for (int mt = 0; mt < 4; ++mt) {
            bf16x8 A = *(const bf16x8*)&sT1[(mt * 16 + lr) * PK2 + kt * 32 + lk];
#pragma unroll
            for (int nt = 0; nt < 2; ++nt)
                acc2[mt][nt] = __builtin_amdgcn_mfma_f32_16x16x32_bf16(A, B2[nt][kt], acc2[mt][nt], 0, 0, 0);
        }

    // ---- epilogue: msg = hv[src] * ssp(acc2) ; atomicAdd agg[dst] ----
#pragma unroll
    for (int mt = 0; mt < 4; ++mt)
#pragma unroll
        for (int nt = 0; nt < 2; ++nt) {
            const int col = cb + nt * 16 + lr;
#pragma unroll
            for (int r = 0; r < 4; ++r) {
                const int row = mt * 16 + (l >> 4) * 4 + r;
                if (e0 + row < nE) {
                    const float he = sspf(acc2[mt][nt][r]);
                    const int s = sSrc[row], d = sDst[row];
                    const float m = HV[(size_t)s * 128 + col] * he;
                    atomicAdd(&AGG[(size_t)d * 128 + col], m);
                }
            }
        }
}

extern "C" void kernel_launch(void* const* d_in, const int* in_sizes, int n_in,
                              void* d_out, int out_size, void* d_ws, size_t ws_size,
                              hipStream_t stream) {
    const float* x    = (const float*)d_in[0];
    const float* e    = (const float*)d_in[1];
    const int*   src  = (const int*)  d_in[2];
    const int*   dst  = (const int*)  d_in[3];
    const float* n1W  = (const float*)d_in[4];
    const float* n1b  = (const float*)d_in[5];
    const float* e1W1 = (const float*)d_in[6];
    const float* e1b1 = (const float*)d_in[7];
    const float* e1W2 = (const float*)d_in[8];
    const float* e1b2 = (const float*)d_in[9];
    const float* o1W  = (const float*)d_in[10];
    const float* o1b  = (const float*)d_in[11];
    const float* n2W  = (const float*)d_in[12];
    const float* n2b  = (const float*)d_in[13];
    const float* e2W1 = (const float*)d_in[14];
    const float* e2b1 = (const float*)d_in[15];
    const float* e2W2 = (const float*)d_in[16];
    const float* e2b2 = (const float*)d_in[17];
    const float* o2W  = (const float*)d_in[18];
    const float* o2b  = (const float*)d_in[19];

    const int N = in_sizes[0] / 128;
    const int E = in_sizes[2];
    float* out = (float*)d_out;

    char* ws = (char*)d_ws;
    const size_t nbytes = (size_t)N * 128 * sizeof(float);
    float* hv   = (float*)(ws);
    float* agg  = (float*)(ws + nbytes);
    float* hbuf = (float*)(ws + 2 * nbytes);

    // converted-weight buffers (bf16, transposed+padded): 2*(9216+17408)*2B = 106.5 KB
    const size_t w1t_elems = 128 * PK1;   // 9216
    const size_t w2t_elems = 128 * PK2;   // 17408
    const size_t wbytes = 2 * (w1t_elems + w2t_elems) * sizeof(unsigned short);
    unsigned short* wbase;
    if (ws_size >= 3 * nbytes + wbytes) {
        wbase = (unsigned short*)(ws + 3 * nbytes);
    } else {
        wbase = (unsigned short*)d_out;   // fallback scratch (safe: overwritten later)
    }
    unsigned short* w1t_1 = wbase;
    unsigned short* w2t_1 = wbase + w1t_elems;
    unsigned short* w1t_2 = wbase + w1t_elems + w2t_elems;
    unsigned short* w2t_2 = wbase + 2 * w1t_elems + w2t_elems;

    const int nodeBlocks = (N + 1) / 2;
    const int edgeBlocks = (E + 63) / 64;

    // pre-convert weights
    convert_wT<<<(128 * PK1 + 255) / 256, 256, 0, stream>>>(e1W1, w1t_1, 64,  PK1);
    convert_wT<<<(128 * PK2 + 255) / 256, 256, 0, stream>>>(e1W2, w2t_1, 128, PK2);
    convert_wT<<<(128 * PK1 + 255) / 256, 256, 0, stream>>>(e2W1, w1t_2, 64,  PK1);
    convert_wT<<<(128 * PK2 + 255) / 256, 256, 0, stream>>>(e2W2, w2t_2, 128, PK2);

    // ---- layer 1 ----
    node_gemm<0><<<nodeBlocks, 256, 0, stream>>>(x, n1W, n1b, hv, N);
    hipMemsetAsync(agg, 0, nbytes, stream);
    edge_mfma<<<edgeBlocks, 256, 0, stream>>>(e, src, dst, hv, w1t_1, e1b1, w2t_1, e1b2, agg, E);
    node_gemm<1><<<nodeBlocks, 256, 0, stream>>>(agg, o1W, o1b, hbuf, N);

    // ---- layer 2 ----
    node_gemm<0><<<nodeBlocks, 256, 0, stream>>>(hbuf, n2W, n2b, hv, N);
    hipMemsetAsync(agg, 0, nbytes, stream);
    edge_mfma<<<edgeBlocks, 256, 0, stream>>>(e, src, dst, hv, w1t_2, e2b1, w2t_2, e2b2, agg, E);
    node_gemm<1><<<nodeBlocks, 256, 0, stream>>>(agg, o2W, o2b, out, N);
}